// Round 1
// baseline (62.756 us; speedup 1.0000x reference)
//
#include <hip/hip_runtime.h>
#include <hip/hip_bf16.h>

typedef __attribute__((ext_vector_type(8))) short bf16x8;   // 8 bf16 = 4 VGPR (MFMA A/B frag)
typedef __attribute__((ext_vector_type(4))) float f32x4;    // MFMA C/D frag

// LDS pitches in bf16 elements (+8 pad -> row stride steps 4 banks -> ~2-way conflicts)
#define PX 136   // sXT  [256][128+8]
#define PA 136   // sAdj [128][128+8]
#define PW 72    // sW   [256][64+8]
#define PG 72    // sAggC[128][64+8]

static __device__ __forceinline__ unsigned short f2b(float f) {
  union { __hip_bfloat16 h; unsigned short u; } cv;
  cv.h = __float2bfloat16(f);
  return cv.u;
}

// Pre-transpose weights to bf16 W^T[h][d] in workspace.
// ws layout (bf16 elems): WT1 @0 (256x128), WT2 @32768 (256x256), WT3 @98304 (256x256)
__global__ void __launch_bounds__(256) gnn_prep(const float* __restrict__ W1,
                                                const float* __restrict__ W2,
                                                const float* __restrict__ W3,
                                                unsigned short* __restrict__ wt) {
  int idx = blockIdx.x * 256 + threadIdx.x;   // 0..65535
  unsigned short* wt1 = wt;
  unsigned short* wt2 = wt + 32768;
  unsigned short* wt3 = wt + 98304;
  if (idx < 32768) {                 // W1: [128][256] -> WT1[h][d]
    int d = idx >> 8, h = idx & 255;
    wt1[h * 128 + d] = f2b(W1[idx]);
  }
  {                                  // W2/W3: [256][256] -> WT[h][d]
    int d = idx >> 8, h = idx & 255;
    wt2[h * 256 + d] = f2b(W2[idx]);
    wt3[h * 256 + d] = f2b(W3[idx]);
  }
}

// One block per graph. 512 threads = 8 waves.
// Wave grids: phase A' (M=64 d-chunk, N=128 i): WGM=2 x WGN=4, 2x2 tiles/wave.
//             phase B  (M=128 i, N=256 h):      WGM=2 x WGN=4, 4x4 tiles/wave.
__global__ void __launch_bounds__(512, 2) gnn_main(
    const float* __restrict__ xin, const float* __restrict__ adjg,
    const float* __restrict__ b1, const float* __restrict__ b2,
    const float* __restrict__ b3, const float* __restrict__ Wh,
    const float* __restrict__ bh, const unsigned short* __restrict__ wt,
    float* __restrict__ out) {
  __shared__ unsigned short sXT[256 * PX];    // X^T: [d][node j]
  __shared__ unsigned short sAdj[128 * PA];   // adj (symmetric, bf16-exact)
  __shared__ unsigned short sW[256 * PW];     // W^T chunk [h][dloc]
  __shared__ unsigned short sAggC[128 * PG];  // AGG chunk [i][dloc]; aliased as fp32 pool at end

  const int g = blockIdx.x;
  const int tid = threadIdx.x;
  const int lane = tid & 63;
  const int w = tid >> 6;
  const int l15 = lane & 15;
  const int l4 = lane >> 4;
  const int wm = w & 1;
  const int wn = w >> 1;

  const float* x0 = xin + (size_t)g * (128 * 128);
  const float* ag = adjg + (size_t)g * (128 * 128);

  // ---- initial loads: adj -> sAdj (straight), x0 -> sXT (transposed) ----
  {
    int row = tid >> 2;            // 0..127
    int c0 = (tid & 3) << 5;       // 0,32,64,96
    const float4* asrc = (const float4*)(ag + row * 128 + c0);
    const float4* xsrc = (const float4*)(x0 + row * 128 + c0);
#pragma unroll
    for (int q = 0; q < 8; ++q) {
      float4 v = asrc[q];
      ushort4 p;
      p.x = f2b(v.x); p.y = f2b(v.y); p.z = f2b(v.z); p.w = f2b(v.w);
      *(ushort4*)&sAdj[row * PA + c0 + q * 4] = p;
    }
#pragma unroll
    for (int q = 0; q < 8; ++q) {  // transpose: sXT[d][j] = x0[j][d]
      float4 v = xsrc[q];
      int d = c0 + q * 4;
      sXT[(d + 0) * PX + row] = f2b(v.x);
      sXT[(d + 1) * PX + row] = f2b(v.y);
      sXT[(d + 2) * PX + row] = f2b(v.z);
      sXT[(d + 3) * PX + row] = f2b(v.w);
    }
  }
  __syncthreads();

  f32x4 accB[4][4];

  for (int l = 0; l < 3; ++l) {
    const int Din = (l == 0) ? 128 : 256;
    const int nck = Din >> 6;
    const unsigned short* wtl = (l == 0) ? wt : (l == 1) ? wt + 32768 : wt + 98304;
    const float* bl = (l == 0) ? b1 : (l == 1) ? b2 : b3;

#pragma unroll
    for (int mi = 0; mi < 4; ++mi)
#pragma unroll
      for (int ni = 0; ni < 4; ++ni)
        accB[mi][ni] = (f32x4){0.f, 0.f, 0.f, 0.f};

    for (int c = 0; c < nck; ++c) {
      // ---- stage W^T chunk [256][64] (overlaps with A' MFMAs below) ----
      {
        int h = tid >> 1;
        int cc = (tid & 1) << 5;
        const unsigned short* src = wtl + h * Din + (c << 6) + cc;
#pragma unroll
        for (int q = 0; q < 4; ++q) {
          bf16x8 v = *(const bf16x8*)(src + q * 8);
          *(bf16x8*)&sW[h * PW + cc + q * 8] = v;
        }
      }
      // ---- phase A': AGGT[d-chunk][i] = sum_j XT[d][j] * adj[j][i] (adj symmetric) ----
      f32x4 accA[2][2];
#pragma unroll
      for (int mi = 0; mi < 2; ++mi)
#pragma unroll
        for (int ni = 0; ni < 2; ++ni)
          accA[mi][ni] = (f32x4){0.f, 0.f, 0.f, 0.f};

#pragma unroll
      for (int ks = 0; ks < 4; ++ks) {   // K = 128 nodes, 32/step
        bf16x8 a[2], b[2];
#pragma unroll
        for (int mi = 0; mi < 2; ++mi) {
          int dr = (c << 6) + wm * 32 + mi * 16 + l15;
          a[mi] = *(const bf16x8*)&sXT[dr * PX + ks * 32 + l4 * 8];
        }
#pragma unroll
        for (int ni = 0; ni < 2; ++ni) {
          int ir = wn * 32 + ni * 16 + l15;
          b[ni] = *(const bf16x8*)&sAdj[ir * PA + ks * 32 + l4 * 8];
        }
#pragma unroll
        for (int mi = 0; mi < 2; ++mi)
#pragma unroll
          for (int ni = 0; ni < 2; ++ni)
            accA[mi][ni] = __builtin_amdgcn_mfma_f32_16x16x32_bf16(a[mi], b[ni], accA[mi][ni], 0, 0, 0);
      }
      // store: acc rows are consecutive d -> 8B contiguous writes as AGG[i][dloc]
#pragma unroll
      for (int mi = 0; mi < 2; ++mi)
#pragma unroll
        for (int ni = 0; ni < 2; ++ni) {
          int dloc = wm * 32 + mi * 16 + l4 * 4;
          int i = wn * 32 + ni * 16 + l15;
          f32x4 v = accA[mi][ni];
          ushort4 p;
          p.x = f2b(v[0]); p.y = f2b(v[1]); p.z = f2b(v[2]); p.w = f2b(v[3]);
          *(ushort4*)&sAggC[i * PG + dloc] = p;
        }
      __syncthreads();
      // ---- phase B partial: accB += AGG_chunk @ W_chunk ----
#pragma unroll
      for (int ks = 0; ks < 2; ++ks) {   // K = 64 chunk, 32/step
        bf16x8 a[4], b[4];
#pragma unroll
        for (int mi = 0; mi < 4; ++mi) {
          int ir = wm * 64 + mi * 16 + l15;
          a[mi] = *(const bf16x8*)&sAggC[ir * PG + ks * 32 + l4 * 8];
        }
#pragma unroll
        for (int ni = 0; ni < 4; ++ni) {
          int hr = wn * 64 + ni * 16 + l15;
          b[ni] = *(const bf16x8*)&sW[hr * PW + ks * 32 + l4 * 8];
        }
#pragma unroll
        for (int mi = 0; mi < 4; ++mi)
#pragma unroll
          for (int ni = 0; ni < 4; ++ni)
            accB[mi][ni] = __builtin_amdgcn_mfma_f32_16x16x32_bf16(a[mi], b[ni], accB[mi][ni], 0, 0, 0);
      }
      __syncthreads();
    } // chunks

    // ---- epilogue: bias + relu ----
    float bias[4];
#pragma unroll
    for (int ni = 0; ni < 4; ++ni) bias[ni] = bl[wn * 64 + ni * 16 + l15];

    if (l < 2) {
      // H[i][h] -> sXT[h][i] (next layer's X^T); acc rows = consecutive i -> 8B writes
#pragma unroll
      for (int ni = 0; ni < 4; ++ni) {
        int h = wn * 64 + ni * 16 + l15;
#pragma unroll
        for (int mi = 0; mi < 4; ++mi) {
          int i0 = wm * 64 + mi * 16 + l4 * 4;
          ushort4 p;
          p.x = f2b(fmaxf(accB[mi][ni][0] + bias[ni], 0.f));
          p.y = f2b(fmaxf(accB[mi][ni][1] + bias[ni], 0.f));
          p.z = f2b(fmaxf(accB[mi][ni][2] + bias[ni], 0.f));
          p.w = f2b(fmaxf(accB[mi][ni][3] + bias[ni], 0.f));
          *(ushort4*)&sXT[h * PX + i0] = p;
        }
      }
      __syncthreads();
    } else {
      // ---- mean pool over nodes + linear head (fp32 throughout) ----
      float* sPool = (float*)sAggC;   // [2][256], sAggC is dead here
      float ps[4];
#pragma unroll
      for (int ni = 0; ni < 4; ++ni) {
        float s = 0.f;
#pragma unroll
        for (int mi = 0; mi < 4; ++mi)
#pragma unroll
          for (int r = 0; r < 4; ++r)
            s += fmaxf(accB[mi][ni][r] + bias[ni], 0.f);
        s += __shfl_xor(s, 16);       // combine l4 groups (same h, different i)
        s += __shfl_xor(s, 32);
        ps[ni] = s;
      }
      if (l4 == 0) {
#pragma unroll
        for (int ni = 0; ni < 4; ++ni)
          sPool[wm * 256 + wn * 64 + ni * 16 + l15] = ps[ni];
      }
      __syncthreads();
      if (w == 0) {
        float acc = 0.f;
#pragma unroll
        for (int q = 0; q < 4; ++q) {
          int h = lane + q * 64;
          acc += (sPool[h] + sPool[256 + h]) * Wh[h];
        }
#pragma unroll
        for (int off = 32; off > 0; off >>= 1) acc += __shfl_xor(acc, off);
        if (lane == 0) out[g] = acc * (1.0f / 128.0f) + bh[0];
      }
    }
  }
}

extern "C" void kernel_launch(void* const* d_in, const int* in_sizes, int n_in,
                              void* d_out, int out_size, void* d_ws, size_t ws_size,
                              hipStream_t stream) {
  const float* xin = (const float*)d_in[0];   // node_features [512,128,128]
  const float* adj = (const float*)d_in[1];   // adj [512,128,128]
  const float* W1  = (const float*)d_in[2];
  const float* b1  = (const float*)d_in[3];
  const float* W2  = (const float*)d_in[4];
  const float* b2  = (const float*)d_in[5];
  const float* W3  = (const float*)d_in[6];
  const float* b3  = (const float*)d_in[7];
  const float* Wh  = (const float*)d_in[8];
  const float* bh  = (const float*)d_in[9];
  unsigned short* wt = (unsigned short*)d_ws; // 327,680 B of bf16 W^T

  gnn_prep<<<256, 256, 0, stream>>>(W1, W2, W3, wt);
  gnn_main<<<512, 512, 0, stream>>>(xin, adj, b1, b2, b3, Wh, bh, wt, (float*)d_out);
}